// Round 7
// baseline (257.082 us; speedup 1.0000x reference)
//
#include <hip/hip_runtime.h>
#include <hip/hip_bf16.h>

typedef __bf16 bf16_t;
typedef __bf16 bf16x4 __attribute__((ext_vector_type(4)));
typedef __bf16 bf16x8 __attribute__((ext_vector_type(8)));
typedef float f32x4 __attribute__((ext_vector_type(4)));

#define B_   2
#define L_   4096
#define DIM_ 1024
#define M_   (B_ * L_)          // 8192 total rows
#define NTASK2_ 272             // attn tasks/batch: mi 0..15, nt 0..2mi+1

// ---- async global->LDS, 16B per lane (wave-uniform LDS base + lane*16) ----
__device__ __forceinline__ void ld_g2l_16(const bf16_t* g, bf16_t* l) {
  __builtin_amdgcn_global_load_lds(
      (__attribute__((address_space(1))) void*)g,
      (__attribute__((address_space(3))) void*)l, 16, 0, 0);
}

// ---- fused fp32 -> bf16 convert (RNE) + zero rowsum accumulator ----
__global__ void cvt_all(const float* __restrict__ hs, const float* __restrict__ wq,
                        const float* __restrict__ wk, bf16_t* __restrict__ hs_b,
                        bf16_t* __restrict__ wq_b, bf16_t* __restrict__ wk_b,
                        float* __restrict__ o) {
  const int N_HS = M_ * DIM_ / 4, N_W = DIM_ * DIM_ / 4;
  int i = blockIdx.x * blockDim.x + threadIdx.x;
  if (i < M_ / 4) ((float4*)o)[i] = float4{0.f, 0.f, 0.f, 0.f};
  const float* s; bf16_t* d; int idx;
  if (i < N_HS)            { s = hs; d = hs_b; idx = i; }
  else if (i < N_HS + N_W) { s = wq; d = wq_b; idx = i - N_HS; }
  else                     { s = wk; d = wk_b; idx = i - N_HS - N_W; }
  float4 v = ((const float4*)s)[idx];
  bf16x4 ov = { (bf16_t)v.x, (bf16_t)v.y, (bf16_t)v.z, (bf16_t)v.w };
  ((bf16x4*)d)[idx] = ov;
}

// ---- 256xBN bt-GEMM core, 8 waves, 3-buffer + TWO barriers per slice ----
// EXACT round-2 structure (measured 59.5us attn / ~95us r3 proj).
// BSEGS=8: B = 128 rows. BSEGS=16: B = 256 rows (segs 16..23 from B0,
// 24..31 from B1). Waves: wm=wave>>1 (4 row groups of 64), wn=wave&1.
// LDS: 3 rotating slice-buffers of (16+BSEGS) segs x 1KB. Segment = 16 rows
// x 32 k, XOR-swizzled (chunk c of row r at c^((r>>1)&3)); staging fetches
// the permuted global chunk so the linear lane*16 LDS write lands swizzled;
// ds_read_b128 is then 2-way conflict (free).
// Iteration s: {ds_read slice s from p0 ; stage slice s+2 -> p2 ; barrier ;
// lgkmcnt(0) ; sched_barrier ; MFMA ; vmcnt(L) (slice s+1 landed, s+2 stays
// in flight -- never drain to 0 mid-loop) ; barrier ; rotate}.
template <int BSEGS>
__device__ __forceinline__ void core256(const bf16_t* __restrict__ A,
                                        const bf16_t* __restrict__ B0,
                                        const bf16_t* __restrict__ B1,
                                        bf16_t* sm, bool active,
                                        f32x4 (&acc)[4][BSEGS / 2]) {
  constexpr int SEGS = 16 + BSEGS;
  constexpr int BUF  = SEGS * 512;
  const int tid  = threadIdx.x;
  const int wave = tid >> 6, lane = tid & 63;
  const int wm = wave >> 1, wn = wave & 1;
  const int quad = lane >> 4, l16 = lane & 15;
  const int srow = lane >> 2;                                  // 0..15 in segment
  const int scol = (((lane & 3) ^ ((lane >> 3) & 3)) * 8);     // swizzled chunk
  const int rsw  = ((l16 >> 1) & 3) * 8;                       // read-side swizzle
  const int loff = l16 * 32 + ((quad * 8) ^ rsw);              // frag lane offset

  const bf16_t* gA0 = A + (size_t)(wave * 16 + srow) * DIM_ + scol;
  const bf16_t* gA1 = A + (size_t)((wave + 8) * 16 + srow) * DIM_ + scol;
  const bf16_t* gB0 = B0 + (size_t)(wave * 16 + srow) * DIM_ + scol;
  const bf16_t* gB1 = gB0;
  if constexpr (BSEGS == 16) gB1 = B1 + (size_t)(wave * 16 + srow) * DIM_ + scol;

  bf16_t* p0 = sm;                 // slice s (read)
  bf16_t* p1 = sm + BUF;           // slice s+1 (in flight)
  bf16_t* p2 = sm + 2 * BUF;       // stage target (slice s+2)

  auto stage = [&](int kk, bf16_t* buf) {
    ld_g2l_16(gA0 + kk, buf + wave * 512);
    ld_g2l_16(gA1 + kk, buf + (wave + 8) * 512);
    ld_g2l_16(gB0 + kk, buf + (16 + wave) * 512);
    if constexpr (BSEGS == 16) ld_g2l_16(gB1 + kk, buf + (24 + wave) * 512);
  };

  stage(0, p0);
  stage(32, p1);
  if constexpr (BSEGS == 16) asm volatile("s_waitcnt vmcnt(4)" ::: "memory");
  else                       asm volatile("s_waitcnt vmcnt(3)" ::: "memory");
  __builtin_amdgcn_s_barrier();    // slice 0 valid block-wide

  for (int s = 0; s < 32; ++s) {
    bf16x8 aF[4], bF[BSEGS / 2];
    if (active) {
#pragma unroll
      for (int rf = 0; rf < 4; ++rf)
        aF[rf] = *(const bf16x8*)(p0 + (wm * 4 + rf) * 512 + loff);
#pragma unroll
      for (int cf = 0; cf < BSEGS / 2; ++cf) {
        int k = (cf & 3) + wn * 4 + (cf >> 2) * 8;
        bF[cf] = *(const bf16x8*)(p0 + (16 + k) * 512 + loff);
      }
    }
    if (s < 30) stage((s + 2) * 32, p2);   // overlapped with ds_reads
    __builtin_amdgcn_s_barrier();
    asm volatile("s_waitcnt lgkmcnt(0)" ::: "memory");  // own frags in regs
    __builtin_amdgcn_sched_barrier(0);
    if (active) {
      __builtin_amdgcn_s_setprio(1);
#pragma unroll
      for (int rf = 0; rf < 4; ++rf)
#pragma unroll
        for (int cf = 0; cf < BSEGS / 2; ++cf)
          acc[rf][cf] = __builtin_amdgcn_mfma_f32_16x16x32_bf16(
              aF[rf], bF[cf], acc[rf][cf], 0, 0, 0);
      __builtin_amdgcn_s_setprio(0);
    }
    if (s < 30) {
      if constexpr (BSEGS == 16) asm volatile("s_waitcnt vmcnt(4)" ::: "memory");
      else                       asm volatile("s_waitcnt vmcnt(3)" ::: "memory");
    } else if (s == 30) {
      asm volatile("s_waitcnt vmcnt(0)" ::: "memory");
    }
    __builtin_amdgcn_s_barrier();   // slice s+1 valid; all reads of s done
    bf16_t* t0 = p0; p0 = p1; p1 = p2; p2 = t0;
  }
}

// ---- projection GEMM + fused RoPE: 256x256 paired-column tiles ----
// Tile covers output cols [n0,n0+128) u [n0+512,n0+640): each thread holds
// both rope partners (acc[rf][cf], acc[rf][cf+4]) -> rope in-register, rope
// kernel eliminated. 256 blocks = exactly 1/CU = one clean generation.
// Direct 2B stores (write amplification proven store-pattern-invariant r3/r5).
// XCD map: XCD x owns m-panels 4x..4x+3 across all 8 (z,n0) groups.
__global__ __launch_bounds__(512, 2)
void proj_gemm(const bf16_t* __restrict__ A, const bf16_t* __restrict__ Wqb,
               const bf16_t* __restrict__ Wkb, bf16_t* __restrict__ Cq,
               bf16_t* __restrict__ Ck) {
  __shared__ __attribute__((aligned(16))) bf16_t sm[3 * 32 * 512];  // 96KB
  const int bid = blockIdx.x;                 // 256 blocks
  const int xcd = bid & 7, slot = bid >> 3;   // slot 0..31
  const int m0 = (xcd * 4 + (slot >> 3)) * 256;
  const int zn = slot & 7;
  const int z = zn >> 2, n0 = (zn & 3) * 128;
  const bf16_t* Wb = z ? Wkb : Wqb;
  bf16_t* Cm = z ? Ck : Cq;

  f32x4 acc[4][8] = {};
  core256<16>(A + (size_t)m0 * DIM_, Wb + (size_t)n0 * DIM_,
              Wb + (size_t)(n0 + 512) * DIM_, sm, true, acc);

  const int tid = threadIdx.x, wave = tid >> 6, lane = tid & 63;
  const int wm = wave >> 1, wn = wave & 1;
  const int quad = lane >> 4, l16 = lane & 15;

  float inv[4];
#pragma unroll
  for (int cf = 0; cf < 4; ++cf) {
    int j = n0 + wn * 64 + cf * 16 + l16;          // pair index 0..511
    inv[cf] = exp2f((float)j * (-5.0f / 512.0f));  // 32^(-2j/1024)
  }
#pragma unroll
  for (int rf = 0; rf < 4; ++rf)
#pragma unroll
    for (int r = 0; r < 4; ++r) {
      int m = m0 + wm * 64 + rf * 16 + quad * 4 + r;  // C/D: row=quad*4+reg
      float posf = (float)(m & (L_ - 1));
#pragma unroll
      for (int cf = 0; cf < 4; ++cf) {
        int j = n0 + wn * 64 + cf * 16 + l16;
        float ang = posf * inv[cf];
        float c = cosf(ang), s = sinf(ang);
        float cb = (float)(bf16_t)c, sb = (float)(bf16_t)s;  // ref rounds
        float x1 = (float)(bf16_t)acc[rf][cf][r];     // ref: astype(bf16) first
        float x2 = (float)(bf16_t)acc[rf][cf + 4][r];
        Cm[(size_t)m * DIM_ + j]       = (bf16_t)(x1 * cb - x2 * sb);
        Cm[(size_t)m * DIM_ + j + 512] = (bf16_t)(x2 * cb + x1 * sb);
      }
    }
}

// ---- causal exp-rowsum: o[b,m] = sum_{n<=m} exp(q_m . k_n / 32) ----
// EXACT round-2 config (measured 59.5us): 256x128 tiles, 544 blocks,
// 72KB LDS -> 2 blocks/CU; XCD chunk map (544 = 8*68, bijective).
__global__ __launch_bounds__(512, 4)
void attn_rowsum(const bf16_t* __restrict__ Q, const bf16_t* __restrict__ Kc,
                 float* __restrict__ o) {
  __shared__ __attribute__((aligned(16))) bf16_t sm[3 * 24 * 512];  // 72KB
  int logical = (blockIdx.x & 7) * 68 + (blockIdx.x >> 3);   // 544 = 8*68
  int b = logical / NTASK2_;
  int t = logical - b * NTASK2_;
  int mi = (int)((sqrtf(4.0f * (float)t + 1.0f) - 1.0f) * 0.5f);
  while ((mi + 1) * (mi + 2) <= t) ++mi;     // (mi+1)^2+(mi+1) <= t
  while (mi * (mi + 1) > t) --mi;            // mi^2+mi > t
  int nt = t - mi * (mi + 1);

  const int tid = threadIdx.x, wave = tid >> 6, lane = tid & 63;
  const int wm = wave >> 1, wn = wave & 1;
  const int quad = lane >> 4, l16 = lane & 15;

  const bf16_t* A  = Q  + (size_t)b * L_ * DIM_ + (size_t)mi * 256 * DIM_;
  const bf16_t* Bp = Kc + (size_t)b * L_ * DIM_ + (size_t)nt * 128 * DIM_;

  // wave-level causal skip: wave rows [mi*256+wm*64, +64) vs cols >= nt*128
  bool active = (mi * 256 + wm * 64 + 63) >= nt * 128;

  f32x4 acc[4][4] = {};
  core256<8>(A, Bp, nullptr, sm, active, acc);

  if (active) {
    const bool masked = (nt >= 2 * mi);   // tile touches the diagonal
#pragma unroll
    for (int rf = 0; rf < 4; ++rf) {
#pragma unroll
      for (int r = 0; r < 4; ++r) {
        int grow = mi * 256 + wm * 64 + rf * 16 + quad * 4 + r;  // row in batch
        float sum = 0.0f;
#pragma unroll
        for (int cf = 0; cf < 4; ++cf) {
          int gcol = nt * 128 + wn * 64 + cf * 16 + l16;
          float e = __expf(acc[rf][cf][r] * 0.03125f);   // /sqrt(1024)
          if (!masked || gcol <= grow) sum += e;
        }
        sum += __shfl_xor(sum, 1);
        sum += __shfl_xor(sum, 2);
        sum += __shfl_xor(sum, 4);
        sum += __shfl_xor(sum, 8);
        if (l16 == 0)
          atomicAdd(&o[b * L_ + grow], sum);
      }
    }
  }
}

// ---- tiny MLP epilogue ----
__global__ __launch_bounds__(256)
void mlp_out_kernel(const float* __restrict__ o, const float* __restrict__ fc1_w,
                    const float* __restrict__ fc1_b, const float* __restrict__ fc2_w,
                    const float* __restrict__ fc2_b, float* __restrict__ out) {
  const int R = 16;
  int row0 = blockIdx.x * R;
  int tid = threadIdx.x;
  __shared__ float h[R][16];
  {
    int rl = tid >> 4, i = tid & 15;
    float s = o[row0 + rl];
    h[rl][i] = fmaxf(fc1_w[i] * s + fc1_b[i], 0.0f);
  }
  __syncthreads();
  int d = tid * 4;
  float w[4][16];
#pragma unroll
  for (int c = 0; c < 4; ++c)
#pragma unroll
    for (int i = 0; i < 16; ++i) w[c][i] = fc2_w[(d + c) * 16 + i];
  float4 bb = *(const float4*)(fc2_b + d);
  for (int rl = 0; rl < R; ++rl) {
    float4 v = bb;
#pragma unroll
    for (int i = 0; i < 16; ++i) {
      float hv = h[rl][i];
      v.x += w[0][i] * hv; v.y += w[1][i] * hv;
      v.z += w[2][i] * hv; v.w += w[3][i] * hv;
    }
    *(float4*)(out + (size_t)(row0 + rl) * DIM_ + d) = v;
  }
}

extern "C" void kernel_launch(void* const* d_in, const int* in_sizes, int n_in,
                              void* d_out, int out_size, void* d_ws, size_t ws_size,
                              hipStream_t stream) {
  const float* hs    = (const float*)d_in[0];
  const float* Wq    = (const float*)d_in[1];
  const float* Wk    = (const float*)d_in[2];
  const float* fc1_w = (const float*)d_in[3];
  const float* fc1_b = (const float*)d_in[4];
  const float* fc2_w = (const float*)d_in[5];
  const float* fc2_b = (const float*)d_in[6];
  float* out = (float*)d_out;

  char* ws = (char*)d_ws;
  bf16_t* hs_bf = (bf16_t*)ws; ws += (size_t)M_ * DIM_ * 2;
  bf16_t* wq_bf = (bf16_t*)ws; ws += (size_t)DIM_ * DIM_ * 2;
  bf16_t* wk_bf = (bf16_t*)ws; ws += (size_t)DIM_ * DIM_ * 2;
  bf16_t* q_bf  = (bf16_t*)ws; ws += (size_t)M_ * DIM_ * 2;
  bf16_t* k_bf  = (bf16_t*)ws; ws += (size_t)M_ * DIM_ * 2;
  float*  o     = (float*)ws;  // M_ floats

  const int n4 = (M_ * DIM_ + 2 * DIM_ * DIM_) / 4;
  cvt_all<<<n4 / 256, 256, 0, stream>>>(hs, Wq, Wk, hs_bf, wq_bf, wk_bf, o);

  proj_gemm<<<256, 512, 0, stream>>>(hs_bf, wq_bf, wk_bf, q_bf, k_bf);

  attn_rowsum<<<544, 512, 0, stream>>>(q_bf, k_bf, o);

  mlp_out_kernel<<<M_ / 16, 256, 0, stream>>>(o, fc1_w, fc1_b, fc2_w, fc2_b, out);
}

// Round 8
// 236.161 us; speedup vs baseline: 1.0886x; 1.0886x over previous
//
#include <hip/hip_runtime.h>
#include <hip/hip_bf16.h>

typedef __bf16 bf16_t;
typedef __bf16 bf16x4 __attribute__((ext_vector_type(4)));
typedef __bf16 bf16x8 __attribute__((ext_vector_type(8)));
typedef float f32x4 __attribute__((ext_vector_type(4)));

#define B_   2
#define L_   4096
#define DIM_ 1024
#define M_   (B_ * L_)          // 8192 total rows
#define NTASK2_ 272             // attn tasks/batch: mi 0..15, nt 0..2mi+1

// ---- async global->LDS, 16B per lane (wave-uniform LDS base + lane*16) ----
__device__ __forceinline__ void ld_g2l_16(const bf16_t* g, bf16_t* l) {
  __builtin_amdgcn_global_load_lds(
      (__attribute__((address_space(1))) void*)g,
      (__attribute__((address_space(3))) void*)l, 16, 0, 0);
}

// ---- fused fp32 -> bf16 convert (RNE) + zero rowsum accumulator ----
__global__ void cvt_all(const float* __restrict__ hs, const float* __restrict__ wq,
                        const float* __restrict__ wk, bf16_t* __restrict__ hs_b,
                        bf16_t* __restrict__ wq_b, bf16_t* __restrict__ wk_b,
                        float* __restrict__ o) {
  const int N_HS = M_ * DIM_ / 4, N_W = DIM_ * DIM_ / 4;
  int i = blockIdx.x * blockDim.x + threadIdx.x;
  if (i < M_ / 4) ((float4*)o)[i] = float4{0.f, 0.f, 0.f, 0.f};
  const float* s; bf16_t* d; int idx;
  if (i < N_HS)            { s = hs; d = hs_b; idx = i; }
  else if (i < N_HS + N_W) { s = wq; d = wq_b; idx = i - N_HS; }
  else                     { s = wk; d = wk_b; idx = i - N_HS - N_W; }
  float4 v = ((const float4*)s)[idx];
  bf16x4 ov = { (bf16_t)v.x, (bf16_t)v.y, (bf16_t)v.z, (bf16_t)v.w };
  ((bf16x4*)d)[idx] = ov;
}

// ---- 256x128 bt-GEMM core, 8 waves, 3-buffer + two barriers per slice ----
// EXACT round-2/round-7 measured structure (59.5us attn). 72KB LDS ->
// 2 blocks/CU. B rows come from two panels: segs 16..19 <- B0 rows 0..63,
// segs 20..23 <- B1 rows 0..63 (attn passes B1 = B0 + 64*DIM_, identical to
// a contiguous 128-row panel; proj passes the two rope partner panels).
// PAIRK=false: bF[cf] covers k=(cf&3)+wn*4 (attn epilogue layout).
// PAIRK=true : bF[cf] covers k=(cf&1)+wn*2+(cf>>1)*4 so each thread holds
// both rope partners (k and k+4) -> in-register RoPE in proj epilogue.
// Segment = 16 rows x 32 k, XOR-swizzled (chunk c of row r at c^((r>>1)&3));
// staging fetches the permuted global chunk so the linear lane*16 LDS write
// lands swizzled; ds_read_b128 is then 2-way conflict (free).
// Iteration s: {ds_read slice s from p0 ; stage slice s+2 -> p2 ; barrier ;
// lgkmcnt(0) ; sched_barrier ; MFMA ; vmcnt(3) (slice s+1 landed, s+2 stays
// in flight -- never drain to 0 mid-loop) ; barrier ; rotate}.
template <bool PAIRK>
__device__ __forceinline__ void core256(const bf16_t* __restrict__ A,
                                        const bf16_t* __restrict__ B0,
                                        const bf16_t* __restrict__ B1,
                                        bf16_t* sm, bool active,
                                        f32x4 (&acc)[4][4]) {
  constexpr int BUF = 24 * 512;
  const int tid  = threadIdx.x;
  const int wave = tid >> 6, lane = tid & 63;
  const int wm = wave >> 1, wn = wave & 1;
  const int quad = lane >> 4, l16 = lane & 15;
  const int srow = lane >> 2;                                  // 0..15 in segment
  const int scol = (((lane & 3) ^ ((lane >> 3) & 3)) * 8);     // swizzled chunk
  const int rsw  = ((l16 >> 1) & 3) * 8;                       // read-side swizzle
  const int loff = l16 * 32 + ((quad * 8) ^ rsw);              // frag lane offset

  const bf16_t* gA0 = A + (size_t)(wave * 16 + srow) * DIM_ + scol;
  const bf16_t* gA1 = A + (size_t)((wave + 8) * 16 + srow) * DIM_ + scol;
  const bf16_t* gB  = (wave < 4)
      ? B0 + (size_t)(wave * 16 + srow) * DIM_ + scol
      : B1 + (size_t)((wave - 4) * 16 + srow) * DIM_ + scol;

  bf16_t* p0 = sm;                 // slice s (read)
  bf16_t* p1 = sm + BUF;           // slice s+1 (in flight)
  bf16_t* p2 = sm + 2 * BUF;       // stage target (slice s+2)

  auto stage = [&](int kk, bf16_t* buf) {
    ld_g2l_16(gA0 + kk, buf + wave * 512);
    ld_g2l_16(gA1 + kk, buf + (wave + 8) * 512);
    ld_g2l_16(gB + kk, buf + (16 + wave) * 512);
  };

  stage(0, p0);
  stage(32, p1);
  asm volatile("s_waitcnt vmcnt(3)" ::: "memory");
  __builtin_amdgcn_s_barrier();    // slice 0 valid block-wide

  for (int s = 0; s < 32; ++s) {
    bf16x8 aF[4], bF[4];
    if (active) {
#pragma unroll
      for (int rf = 0; rf < 4; ++rf)
        aF[rf] = *(const bf16x8*)(p0 + (wm * 4 + rf) * 512 + loff);
#pragma unroll
      for (int cf = 0; cf < 4; ++cf) {
        int k = PAIRK ? ((cf & 1) + wn * 2 + (cf >> 1) * 4)
                      : ((cf & 3) + wn * 4);
        bF[cf] = *(const bf16x8*)(p0 + (16 + k) * 512 + loff);
      }
    }
    if (s < 30) stage((s + 2) * 32, p2);   // overlapped with ds_reads
    __builtin_amdgcn_s_barrier();
    asm volatile("s_waitcnt lgkmcnt(0)" ::: "memory");  // own frags in regs
    __builtin_amdgcn_sched_barrier(0);
    if (active) {
      __builtin_amdgcn_s_setprio(1);
#pragma unroll
      for (int rf = 0; rf < 4; ++rf)
#pragma unroll
        for (int cf = 0; cf < 4; ++cf)
          acc[rf][cf] = __builtin_amdgcn_mfma_f32_16x16x32_bf16(
              aF[rf], bF[cf], acc[rf][cf], 0, 0, 0);
      __builtin_amdgcn_s_setprio(0);
    }
    if (s < 30)       asm volatile("s_waitcnt vmcnt(3)" ::: "memory");
    else if (s == 30) asm volatile("s_waitcnt vmcnt(0)" ::: "memory");
    __builtin_amdgcn_s_barrier();   // slice s+1 valid; all reads of s done
    bf16_t* t0 = p0; p0 = p1; p1 = p2; p2 = t0;
  }
}

// ---- projection GEMM + fused RoPE: 256x128 split-pair tiles ----
// Tile covers output cols [n0,n0+64) u [n0+512,n0+576): B0 = W rows
// [n0,n0+64), B1 = W rows [n0+512,n0+576). PAIRK frag map puts both rope
// partners (acc[rf][cf], acc[rf][cf+2]) in the same thread -> in-register
// RoPE, rope kernel eliminated. 72KB LDS -> 2 blocks/CU; 512 blocks = one
// clean generation. XCD map: XCD x owns m-panels 4x..4x+3 across all 16
// (z,n0) groups (hs panel L2-resident per XCD).
__global__ __launch_bounds__(512, 4)
void proj_gemm(const bf16_t* __restrict__ A, const bf16_t* __restrict__ Wqb,
               const bf16_t* __restrict__ Wkb, bf16_t* __restrict__ Cq,
               bf16_t* __restrict__ Ck) {
  __shared__ __attribute__((aligned(16))) bf16_t sm[3 * 24 * 512];  // 72KB
  const int bid = blockIdx.x;                 // 512 blocks
  const int xcd = bid & 7, slot = bid >> 3;   // slot 0..63
  const int m0 = (xcd * 4 + (slot >> 4)) * 256;
  const int zn = slot & 15;
  const int z = zn >> 3, n0 = (zn & 7) * 64;  // pair-group base, 0..448
  const bf16_t* Wb = z ? Wkb : Wqb;
  bf16_t* Cm = z ? Ck : Cq;

  f32x4 acc[4][4] = {};
  core256<true>(A + (size_t)m0 * DIM_, Wb + (size_t)n0 * DIM_,
                Wb + (size_t)(n0 + 512) * DIM_, sm, true, acc);

  const int tid = threadIdx.x, wave = tid >> 6, lane = tid & 63;
  const int wm = wave >> 1, wn = wave & 1;
  const int quad = lane >> 4, l16 = lane & 15;

  float inv[2];
#pragma unroll
  for (int c2 = 0; c2 < 2; ++c2) {
    int j = n0 + (c2 + wn * 2) * 16 + l16;         // pair index 0..511
    inv[c2] = exp2f((float)j * (-5.0f / 512.0f));  // 32^(-2j/1024)
  }
#pragma unroll
  for (int rf = 0; rf < 4; ++rf)
#pragma unroll
    for (int r = 0; r < 4; ++r) {
      int m = m0 + wm * 64 + rf * 16 + quad * 4 + r;  // C/D: row=quad*4+reg
      float posf = (float)(m & (L_ - 1));
#pragma unroll
      for (int c2 = 0; c2 < 2; ++c2) {
        int j = n0 + (c2 + wn * 2) * 16 + l16;
        float ang = posf * inv[c2];
        float c = cosf(ang), s = sinf(ang);
        float cb = (float)(bf16_t)c, sb = (float)(bf16_t)s;  // ref rounds
        float x1 = (float)(bf16_t)acc[rf][c2][r];     // ref: astype(bf16) first
        float x2 = (float)(bf16_t)acc[rf][c2 + 2][r];
        Cm[(size_t)m * DIM_ + j]       = (bf16_t)(x1 * cb - x2 * sb);
        Cm[(size_t)m * DIM_ + j + 512] = (bf16_t)(x2 * cb + x1 * sb);
      }
    }
}

// ---- causal exp-rowsum: o[b,m] = sum_{n<=m} exp(q_m . k_n / 32) ----
// EXACT round-2/round-7 measured config (59.5us): 256x128 tiles, 544 blocks,
// 72KB LDS -> 2 blocks/CU; XCD chunk map (544 = 8*68, bijective).
__global__ __launch_bounds__(512, 4)
void attn_rowsum(const bf16_t* __restrict__ Q, const bf16_t* __restrict__ Kc,
                 float* __restrict__ o) {
  __shared__ __attribute__((aligned(16))) bf16_t sm[3 * 24 * 512];  // 72KB
  int logical = (blockIdx.x & 7) * 68 + (blockIdx.x >> 3);   // 544 = 8*68
  int b = logical / NTASK2_;
  int t = logical - b * NTASK2_;
  int mi = (int)((sqrtf(4.0f * (float)t + 1.0f) - 1.0f) * 0.5f);
  while ((mi + 1) * (mi + 2) <= t) ++mi;     // (mi+1)^2+(mi+1) <= t
  while (mi * (mi + 1) > t) --mi;            // mi^2+mi > t
  int nt = t - mi * (mi + 1);

  const int tid = threadIdx.x, wave = tid >> 6, lane = tid & 63;
  const int wm = wave >> 1, wn = wave & 1;
  const int quad = lane >> 4, l16 = lane & 15;

  const bf16_t* A  = Q  + (size_t)b * L_ * DIM_ + (size_t)mi * 256 * DIM_;
  const bf16_t* Bp = Kc + (size_t)b * L_ * DIM_ + (size_t)nt * 128 * DIM_;

  // wave-level causal skip: wave rows [mi*256+wm*64, +64) vs cols >= nt*128
  bool active = (mi * 256 + wm * 64 + 63) >= nt * 128;

  f32x4 acc[4][4] = {};
  core256<false>(A, Bp, Bp + (size_t)64 * DIM_, sm, active, acc);

  if (active) {
    const bool masked = (nt >= 2 * mi);   // tile touches the diagonal
#pragma unroll
    for (int rf = 0; rf < 4; ++rf) {
#pragma unroll
      for (int r = 0; r < 4; ++r) {
        int grow = mi * 256 + wm * 64 + rf * 16 + quad * 4 + r;  // row in batch
        float sum = 0.0f;
#pragma unroll
        for (int cf = 0; cf < 4; ++cf) {
          int gcol = nt * 128 + wn * 64 + cf * 16 + l16;
          float e = __expf(acc[rf][cf][r] * 0.03125f);   // /sqrt(1024)
          if (!masked || gcol <= grow) sum += e;
        }
        sum += __shfl_xor(sum, 1);
        sum += __shfl_xor(sum, 2);
        sum += __shfl_xor(sum, 4);
        sum += __shfl_xor(sum, 8);
        if (l16 == 0)
          atomicAdd(&o[b * L_ + grow], sum);
      }
    }
  }
}

// ---- tiny MLP epilogue ----
__global__ __launch_bounds__(256)
void mlp_out_kernel(const float* __restrict__ o, const float* __restrict__ fc1_w,
                    const float* __restrict__ fc1_b, const float* __restrict__ fc2_w,
                    const float* __restrict__ fc2_b, float* __restrict__ out) {
  const int R = 16;
  int row0 = blockIdx.x * R;
  int tid = threadIdx.x;
  __shared__ float h[R][16];
  {
    int rl = tid >> 4, i = tid & 15;
    float s = o[row0 + rl];
    h[rl][i] = fmaxf(fc1_w[i] * s + fc1_b[i], 0.0f);
  }
  __syncthreads();
  int d = tid * 4;
  float w[4][16];
#pragma unroll
  for (int c = 0; c < 4; ++c)
#pragma unroll
    for (int i = 0; i < 16; ++i) w[c][i] = fc2_w[(d + c) * 16 + i];
  float4 bb = *(const float4*)(fc2_b + d);
  for (int rl = 0; rl < R; ++rl) {
    float4 v = bb;
#pragma unroll
    for (int i = 0; i < 16; ++i) {
      float hv = h[rl][i];
      v.x += w[0][i] * hv; v.y += w[1][i] * hv;
      v.z += w[2][i] * hv; v.w += w[3][i] * hv;
    }
    *(float4*)(out + (size_t)(row0 + rl) * DIM_ + d) = v;
  }
}

extern "C" void kernel_launch(void* const* d_in, const int* in_sizes, int n_in,
                              void* d_out, int out_size, void* d_ws, size_t ws_size,
                              hipStream_t stream) {
  const float* hs    = (const float*)d_in[0];
  const float* Wq    = (const float*)d_in[1];
  const float* Wk    = (const float*)d_in[2];
  const float* fc1_w = (const float*)d_in[3];
  const float* fc1_b = (const float*)d_in[4];
  const float* fc2_w = (const float*)d_in[5];
  const float* fc2_b = (const float*)d_in[6];
  float* out = (float*)d_out;

  char* ws = (char*)d_ws;
  bf16_t* hs_bf = (bf16_t*)ws; ws += (size_t)M_ * DIM_ * 2;
  bf16_t* wq_bf = (bf16_t*)ws; ws += (size_t)DIM_ * DIM_ * 2;
  bf16_t* wk_bf = (bf16_t*)ws; ws += (size_t)DIM_ * DIM_ * 2;
  bf16_t* q_bf  = (bf16_t*)ws; ws += (size_t)M_ * DIM_ * 2;
  bf16_t* k_bf  = (bf16_t*)ws; ws += (size_t)M_ * DIM_ * 2;
  float*  o     = (float*)ws;  // M_ floats

  const int n4 = (M_ * DIM_ + 2 * DIM_ * DIM_) / 4;
  cvt_all<<<n4 / 256, 256, 0, stream>>>(hs, Wq, Wk, hs_bf, wq_bf, wk_bf, o);

  proj_gemm<<<512, 512, 0, stream>>>(hs_bf, wq_bf, wk_bf, q_bf, k_bf);

  attn_rowsum<<<544, 512, 0, stream>>>(q_bf, k_bf, o);

  mlp_out_kernel<<<M_ / 16, 256, 0, stream>>>(o, fc1_w, fc1_b, fc2_w, fc2_b, out);
}